// Round 11
// baseline (418.268 us; speedup 1.0000x reference)
//
#include <hip/hip_runtime.h>
#include <math.h>

#define FEAT 64
#define NKERN 3

typedef __attribute__((ext_vector_type(8))) short short8;
typedef __attribute__((ext_vector_type(4))) float float4v;

__device__ __forceinline__ unsigned short f2bf(float f) {
    unsigned int u = __float_as_uint(f);
    u = (u + 0x7fffu + ((u >> 16) & 1u)) >> 16;   // round-to-nearest-even
    return (unsigned short)u;
}
__device__ __forceinline__ float bf2f(unsigned short b) {
    return __uint_as_float(((unsigned int)b) << 16);
}
__device__ __forceinline__ float tanh_fast(float x) {
    x = fminf(fmaxf(x, -20.f), 20.f);
    float ex = exp2f(x * 2.885390082f);      // e^(2x)
    return (ex - 1.f) / (ex + 1.f);
}
__device__ __forceinline__ float exp_fast(float x) {
    return exp2f(x * 1.44269504f);
}

// Fused prep: [0,castN4) bf16-cast of feat; [castN4,+wpN) fcW -> frag-tiled
// B hi/lo; [+wpN, +e) per-edge Gaussian weights for all layers (fast math).
__global__ __launch_bounds__(256) void prep_kernel(
    const float* __restrict__ feat, unsigned short* __restrict__ h0,
    const float* __restrict__ fcW,
    unsigned short* __restrict__ Bth, unsigned short* __restrict__ Btl,
    const float* __restrict__ pseudo,
    const float* __restrict__ projW, const float* __restrict__ projB,
    const float* __restrict__ mu, const float* __restrict__ isg,
    float* __restrict__ wbuf3,
    int castN4, int wpN, int n_edges, int n_layers)
{
    int idx = blockIdx.x * 256 + threadIdx.x;
    if (idx < castN4) {
        float4 v = ((const float4*)feat)[idx];
        ushort4 o;
        o.x = f2bf(v.x); o.y = f2bf(v.y); o.z = f2bf(v.z); o.w = f2bf(v.w);
        ((ushort4*)h0)[idx] = o;
        return;
    }
    idx -= castN4;
    if (idx < wpN) {
        int l   = idx / (FEAT * 192);
        int rem = idx - l * (FEAT * 192);
        int f   = rem / 192;
        int jp  = rem - f * 192;
        int k = jp >> 6, j = jp & 63;
        float v = fcW[(size_t)l * 12288 + j * 192 + k * 64 + f];
        unsigned short hi = f2bf(v);
        int dst = l * 12288 +
                  ((((f >> 4) * 6 + (jp >> 5)) * 4 + ((jp >> 3) & 3)) * 16 + (f & 15)) * 8 +
                  (jp & 7);
        Bth[dst] = hi;
        Btl[dst] = f2bf(v - bf2f(hi));
        return;
    }
    idx -= wpN;
    if (idx >= n_edges) return;
    float2 p = ((const float2*)pseudo)[idx];
    for (int l = 0; l < n_layers; ++l) {
        const float* pw = projW + l * 4;
        const float* pb = projB + l * 2;
        const float* m_ = mu  + l * 6;
        const float* s_ = isg + l * 6;
        float u0 = tanh_fast(fmaf(p.x, pw[0], fmaf(p.y, pw[2], pb[0])));
        float u1 = tanh_fast(fmaf(p.x, pw[1], fmaf(p.y, pw[3], pb[1])));
        float d0, d1, s0, s1;
        d0 = u0 - m_[0]; d1 = u1 - m_[1]; s0 = s_[0]; s1 = s_[1];
        float w0 = exp_fast(-0.5f * (d0*d0*s0*s0 + d1*d1*s1*s1));
        d0 = u0 - m_[2]; d1 = u1 - m_[3]; s0 = s_[2]; s1 = s_[3];
        float w1 = exp_fast(-0.5f * (d0*d0*s0*s0 + d1*d1*s1*s1));
        d0 = u0 - m_[4]; d1 = u1 - m_[5]; s0 = s_[4]; s1 = s_[5];
        float w2 = exp_fast(-0.5f * (d0*d0*s0*s0 + d1*d1*s1*s1));
        float* wp = wbuf3 + ((size_t)l * n_edges + idx) * 3;
        wp[0] = w0; wp[1] = w1; wp[2] = w2;
    }
}

// One fused layer. Block = 16 waves = 16 nodes = one MFMA row-tile.
// Phase 0: cooperatively stage this block's contiguous CSR edge span
//   (colind 2KB + weights k-major 6KB) into LDS with coalesced loads.
// Phase 1: wave = node, lane = feature; colind/weights via in-order
//   broadcast ds_reads (no SMEM serialization); 32 gathers in flight.
//   A-frags -> padded LDS tile (strides 544/136 shorts: conflict-free).
// Phase 2: waves 0-3 MFMA vs pre-tiled resident B hi/lo; store h/out.
__global__ __launch_bounds__(1024, 8) void layer_kernel(
    const unsigned short* __restrict__ h,    // [N, 64] bf16
    const int*   __restrict__ rowptr,        // [N+1]
    const int*   __restrict__ colind,        // [E]
    const float* __restrict__ wbuf,          // [E, 3] this layer
    const unsigned short* __restrict__ Bth,  // frag-tiled, this layer
    const unsigned short* __restrict__ Btl,
    float* __restrict__ out,                 // [N,64] fp32 (last layer)
    unsigned short* __restrict__ hnext,      // [N,64] bf16 (mid layers)
    int n_nodes, int last_layer)
{
    __shared__ int   sCol[512];
    __shared__ float sW[3 * 512];                      // k-major [3][512]
    __shared__ __align__(16) unsigned short Atile[6 * 544];  // padded frag tile
    int tid  = threadIdx.x;
    int wv   = tid >> 6;          // 0..15 = node row m within tile
    int lane = tid & 63;
    int t0   = blockIdx.x * 16;
    int t1   = t0 + 16 < n_nodes ? t0 + 16 : n_nodes;
    int rb0  = rowptr[t0];
    int esum = rowptr[t1] - rb0;
    int fast = (esum > 0 && esum <= 512);

    if (fast) {
        for (int i = tid; i < esum; i += 1024)
            sCol[i] = colind[rb0 + i];
        for (int d = tid; d < esum * 3; d += 1024) {
            float val = wbuf[(size_t)rb0 * 3 + d];     // coalesced
            int e = d / 3, k = d - e * 3;
            sW[k * 512 + e] = val;
        }
    }
    __syncthreads();

    int node = t0 + wv;
    float a0 = 0.f, a1 = 0.f, a2 = 0.f;
    if (node < n_nodes) {
        int nu  = __builtin_amdgcn_readfirstlane(node);
        int r0  = rowptr[nu];
        int deg = rowptr[nu + 1] - r0;
        if (fast) {
            int o = r0 - rb0;
            if (deg == 32) {
                unsigned short v[32];
                #pragma unroll
                for (int i = 0; i < 32; ++i)
                    v[i] = h[(size_t)sCol[o + i] * FEAT + lane];  // 128B gather
                #pragma unroll
                for (int i = 0; i < 32; ++i) {
                    float vf = bf2f(v[i]);
                    a0 = fmaf(sW[o + i],        vf, a0);
                    a1 = fmaf(sW[512 + o + i],  vf, a1);
                    a2 = fmaf(sW[1024 + o + i], vf, a2);
                }
            } else {
                for (int i = 0; i < deg; ++i) {
                    float vf = bf2f(h[(size_t)sCol[o + i] * FEAT + lane]);
                    a0 = fmaf(sW[o + i],        vf, a0);
                    a1 = fmaf(sW[512 + o + i],  vf, a1);
                    a2 = fmaf(sW[1024 + o + i], vf, a2);
                }
            }
        } else {
            for (int i = 0; i < deg; ++i) {
                int cc = colind[r0 + i];
                float vf = bf2f(h[(size_t)cc * FEAT + lane]);
                const float* wp = wbuf + (size_t)(r0 + i) * 3;
                a0 = fmaf(wp[0], vf, a0);
                a1 = fmaf(wp[1], vf, a1);
                a2 = fmaf(wp[2], vf, a2);
            }
        }
    }
    // padded A-frag store: jp=lane(+64,+128): ks=jp>>5, q=(jp>>3)&3, e=jp&7
    int base = (lane >> 5) * 544 + ((lane >> 3) & 3) * 136 + wv * 8 + (lane & 7);
    Atile[base]        = f2bf(a0);
    Atile[base + 1088] = f2bf(a1);   // +2 ks blocks
    Atile[base + 2176] = f2bf(a2);   // +4 ks blocks
    __syncthreads();

    if (wv < 4) {
        int w  = wv;            // f-tile
        int q  = lane >> 4;
        int nn = lane & 15;
        const unsigned short* bt0 = Bth + (((w * 6) * 4 + q) * 16 + nn) * 8;
        const unsigned short* bt1 = Btl + (((w * 6) * 4 + q) * 16 + nn) * 8;
        float4v acc = (float4v){0.f, 0.f, 0.f, 0.f};
        #pragma unroll
        for (int ks = 0; ks < 6; ++ks) {
            short8 ah = *(const short8*)&Atile[ks * 544 + q * 136 + nn * 8];
            short8 bh = *(const short8*)(bt0 + ks * 512);
            short8 bl = *(const short8*)(bt1 + ks * 512);
            acc = __builtin_amdgcn_mfma_f32_16x16x32_bf16(ah, bh, acc, 0, 0, 0);
            acc = __builtin_amdgcn_mfma_f32_16x16x32_bf16(ah, bl, acc, 0, 0, 0);
        }
        // D: col f = w*16+nn, row = t0 + q*4 + r
        #pragma unroll
        for (int r = 0; r < 4; ++r) {
            int row = t0 + q * 4 + r;
            if (row < n_nodes) {
                if (last_layer)
                    out[(size_t)row * 64 + w * 16 + nn] = acc[r];
                else
                    hnext[(size_t)row * 64 + w * 16 + nn] = f2bf(acc[r]);
            }
        }
    }
}

extern "C" void kernel_launch(void* const* d_in, const int* in_sizes, int n_in,
                              void* d_out, int out_size, void* d_ws, size_t ws_size,
                              hipStream_t stream)
{
    const float* feat   = (const float*)d_in[0];   // [N, 64]
    const float* pseudo = (const float*)d_in[1];   // [E, 2]
    const int*   rowptr = (const int*)d_in[2];     // [N+1]
    const int*   colind = (const int*)d_in[3];     // [E]
    const float* projW  = (const float*)d_in[4];   // [L, 2, 2]
    const float* projB  = (const float*)d_in[5];   // [L, 2]
    const float* fcW    = (const float*)d_in[6];   // [L, 64, 192]
    const float* mu     = (const float*)d_in[7];   // [L, 3, 2]
    const float* isg    = (const float*)d_in[8];   // [L, 3, 2]
    float* out = (float*)d_out;

    int n  = in_sizes[0] / FEAT;                        // 50000
    int e  = in_sizes[3];                               // 1.6M
    int n_layers = in_sizes[6] / (FEAT * NKERN * FEAT); // 3

    unsigned short* hbA = (unsigned short*)d_ws;                  // n*64
    unsigned short* hbB = hbA + (size_t)n * FEAT;                 // n*64
    unsigned short* Bth = hbB + (size_t)n * FEAT;                 // L*12288
    unsigned short* Btl = Bth + (size_t)n_layers * 12288;         // L*12288
    float* wbuf3 = (float*)(Btl + (size_t)n_layers * 12288);      // L*e*3

    int castN4 = n * FEAT / 4;
    int wpN    = n_layers * FEAT * 192;
    int prepTotal = castN4 + wpN + e;

    dim3 blk(256);
    dim3 prepGrid((prepTotal + 255) / 256);
    dim3 layerGrid((n + 15) / 16);
    dim3 layerBlk(1024);

    prep_kernel<<<prepGrid, blk, 0, stream>>>(
        feat, hbA, fcW, Bth, Btl, pseudo, projW, projB, mu, isg, wbuf3,
        castN4, wpN, e, n_layers);

    const unsigned short* hin = hbA;
    for (int l = 0; l < n_layers; ++l) {
        int last = (l == n_layers - 1);
        unsigned short* hb_out = (l == 0) ? hbB : hbA;
        layer_kernel<<<layerGrid, layerBlk, 0, stream>>>(
            hin, rowptr, colind, wbuf3 + (size_t)l * e * 3,
            Bth + (size_t)l * 12288, Btl + (size_t)l * 12288,
            out, hb_out, n, last);
        hin = hb_out;
    }
}

// Round 12
// 358.667 us; speedup vs baseline: 1.1662x; 1.1662x over previous
//
#include <hip/hip_runtime.h>
#include <math.h>

#define FEAT 64
#define NKERN 3

typedef __attribute__((ext_vector_type(8))) short short8;
typedef __attribute__((ext_vector_type(4))) float float4v;

__device__ __forceinline__ unsigned short f2bf(float f) {
    unsigned int u = __float_as_uint(f);
    u = (u + 0x7fffu + ((u >> 16) & 1u)) >> 16;   // round-to-nearest-even
    return (unsigned short)u;
}
__device__ __forceinline__ float bf2f(unsigned short b) {
    return __uint_as_float(((unsigned int)b) << 16);
}
__device__ __forceinline__ float tanh_fast(float x) {
    x = fminf(fmaxf(x, -20.f), 20.f);
    float ex = exp2f(x * 2.885390082f);      // e^(2x)
    return (ex - 1.f) / (ex + 1.f);
}
__device__ __forceinline__ float exp_fast(float x) {
    return exp2f(x * 1.44269504f);
}

// Fused prep: [0,castN4) bf16-cast of feat; [castN4,+wpN) fcW -> frag-tiled
// B hi/lo; [+wpN, +e) per-edge Gaussian weights for all layers (fast math).
__global__ __launch_bounds__(256) void prep_kernel(
    const float* __restrict__ feat, unsigned short* __restrict__ h0,
    const float* __restrict__ fcW,
    unsigned short* __restrict__ Bth, unsigned short* __restrict__ Btl,
    const float* __restrict__ pseudo,
    const float* __restrict__ projW, const float* __restrict__ projB,
    const float* __restrict__ mu, const float* __restrict__ isg,
    float* __restrict__ wbuf3,
    int castN4, int wpN, int n_edges, int n_layers)
{
    int idx = blockIdx.x * 256 + threadIdx.x;
    if (idx < castN4) {
        float4 v = ((const float4*)feat)[idx];
        ushort4 o;
        o.x = f2bf(v.x); o.y = f2bf(v.y); o.z = f2bf(v.z); o.w = f2bf(v.w);
        ((ushort4*)h0)[idx] = o;
        return;
    }
    idx -= castN4;
    if (idx < wpN) {
        int l   = idx / (FEAT * 192);
        int rem = idx - l * (FEAT * 192);
        int f   = rem / 192;
        int jp  = rem - f * 192;
        int k = jp >> 6, j = jp & 63;
        float v = fcW[(size_t)l * 12288 + j * 192 + k * 64 + f];
        unsigned short hi = f2bf(v);
        int dst = l * 12288 +
                  ((((f >> 4) * 6 + (jp >> 5)) * 4 + ((jp >> 3) & 3)) * 16 + (f & 15)) * 8 +
                  (jp & 7);
        Bth[dst] = hi;
        Btl[dst] = f2bf(v - bf2f(hi));
        return;
    }
    idx -= wpN;
    if (idx >= n_edges) return;
    float2 p = ((const float2*)pseudo)[idx];
    for (int l = 0; l < n_layers; ++l) {
        const float* pw = projW + l * 4;
        const float* pb = projB + l * 2;
        const float* m_ = mu  + l * 6;
        const float* s_ = isg + l * 6;
        float u0 = tanh_fast(fmaf(p.x, pw[0], fmaf(p.y, pw[2], pb[0])));
        float u1 = tanh_fast(fmaf(p.x, pw[1], fmaf(p.y, pw[3], pb[1])));
        float d0, d1, s0, s1;
        d0 = u0 - m_[0]; d1 = u1 - m_[1]; s0 = s_[0]; s1 = s_[1];
        float w0 = exp_fast(-0.5f * (d0*d0*s0*s0 + d1*d1*s1*s1));
        d0 = u0 - m_[2]; d1 = u1 - m_[3]; s0 = s_[2]; s1 = s_[3];
        float w1 = exp_fast(-0.5f * (d0*d0*s0*s0 + d1*d1*s1*s1));
        d0 = u0 - m_[4]; d1 = u1 - m_[5]; s0 = s_[4]; s1 = s_[5];
        float w2 = exp_fast(-0.5f * (d0*d0*s0*s0 + d1*d1*s1*s1));
        float* wp = wbuf3 + ((size_t)l * n_edges + idx) * 3;
        wp[0] = w0; wp[1] = w1; wp[2] = w2;
    }
}

// One fused layer. Block = 16 waves = 32 nodes = TWO MFMA row-tiles.
// Each wave gathers 2 nodes back-to-back (64 loads issued before any
// consumption -> deep MLP; launch_bounds(1024,4) gives VGPR cap 128 so the
// whole batch stays in registers). colind/wbuf on the SCALAR pipe (s_load).
// A-frags -> padded LDS tiles (strides 544/136: conflict-free). Phase 2:
// waves 0-7 (4 per tile) MFMA vs pre-tiled resident B hi/lo; store h/out.
__global__ __launch_bounds__(1024, 4) void layer_kernel(
    const unsigned short* __restrict__ h,    // [N, 64] bf16
    const int*   __restrict__ rowptr,        // [N+1]
    const int*   __restrict__ colind,        // [E]
    const float* __restrict__ wbuf,          // [E, 3] this layer
    const unsigned short* __restrict__ Bth,  // frag-tiled, this layer
    const unsigned short* __restrict__ Btl,
    float* __restrict__ out,                 // [N,64] fp32 (last layer)
    unsigned short* __restrict__ hnext,      // [N,64] bf16 (mid layers)
    int n_nodes, int last_layer)
{
    __shared__ __align__(16) unsigned short Atile[2][6 * 544];
    int tid  = threadIdx.x;
    int wv   = tid >> 6;          // 0..15 = row m within each tile
    int lane = tid & 63;
    int t0   = blockIdx.x * 32;

    int nodeA = t0 + wv;
    int nodeB = t0 + 16 + wv;
    int nuA = __builtin_amdgcn_readfirstlane(nodeA < n_nodes ? nodeA : 0);
    int nuB = __builtin_amdgcn_readfirstlane(nodeB < n_nodes ? nodeB : 0);
    int r0A = rowptr[nuA]; int degA = rowptr[nuA + 1] - r0A;
    int r0B = rowptr[nuB]; int degB = rowptr[nuB + 1] - r0B;

    float aA0 = 0.f, aA1 = 0.f, aA2 = 0.f;
    float aB0 = 0.f, aB1 = 0.f, aB2 = 0.f;
    if (degA == 32 && degB == 32) {
        unsigned short vA[32], vB[32];
        #pragma unroll
        for (int i = 0; i < 32; ++i) {
            int cc = colind[r0A + i];             // uniform -> s_load
            vA[i] = h[(size_t)cc * FEAT + lane];  // coalesced 128B gather
        }
        #pragma unroll
        for (int i = 0; i < 32; ++i) {
            int cc = colind[r0B + i];
            vB[i] = h[(size_t)cc * FEAT + lane];
        }
        #pragma unroll
        for (int i = 0; i < 32; ++i) {
            const float* wp = wbuf + (size_t)(r0A + i) * 3;  // uniform s_load
            float vf = bf2f(vA[i]);
            aA0 = fmaf(wp[0], vf, aA0);
            aA1 = fmaf(wp[1], vf, aA1);
            aA2 = fmaf(wp[2], vf, aA2);
        }
        #pragma unroll
        for (int i = 0; i < 32; ++i) {
            const float* wp = wbuf + (size_t)(r0B + i) * 3;
            float vf = bf2f(vB[i]);
            aB0 = fmaf(wp[0], vf, aB0);
            aB1 = fmaf(wp[1], vf, aB1);
            aB2 = fmaf(wp[2], vf, aB2);
        }
    } else {
        for (int i = 0; i < degA; ++i) {
            int cc = colind[r0A + i];
            float vf = bf2f(h[(size_t)cc * FEAT + lane]);
            const float* wp = wbuf + (size_t)(r0A + i) * 3;
            aA0 = fmaf(wp[0], vf, aA0);
            aA1 = fmaf(wp[1], vf, aA1);
            aA2 = fmaf(wp[2], vf, aA2);
        }
        for (int i = 0; i < degB; ++i) {
            int cc = colind[r0B + i];
            float vf = bf2f(h[(size_t)cc * FEAT + lane]);
            const float* wp = wbuf + (size_t)(r0B + i) * 3;
            aB0 = fmaf(wp[0], vf, aB0);
            aB1 = fmaf(wp[1], vf, aB1);
            aB2 = fmaf(wp[2], vf, aB2);
        }
    }
    // padded A-frag store: jp=lane(+64,+128): ks=jp>>5, q=(jp>>3)&3, e=jp&7
    int base = (lane >> 5) * 544 + ((lane >> 3) & 3) * 136 + wv * 8 + (lane & 7);
    Atile[0][base]        = f2bf(aA0);
    Atile[0][base + 1088] = f2bf(aA1);
    Atile[0][base + 2176] = f2bf(aA2);
    Atile[1][base]        = f2bf(aB0);
    Atile[1][base + 1088] = f2bf(aB1);
    Atile[1][base + 2176] = f2bf(aB2);
    __syncthreads();

    if (wv < 8) {
        int tile = wv >> 2;     // 0: rows t0..t0+15, 1: rows t0+16..t0+31
        int w    = wv & 3;      // f-tile
        int q    = lane >> 4;
        int nn   = lane & 15;
        const unsigned short* bt0 = Bth + (((w * 6) * 4 + q) * 16 + nn) * 8;
        const unsigned short* bt1 = Btl + (((w * 6) * 4 + q) * 16 + nn) * 8;
        float4v acc = (float4v){0.f, 0.f, 0.f, 0.f};
        #pragma unroll
        for (int ks = 0; ks < 6; ++ks) {
            short8 ah = *(const short8*)&Atile[tile][ks * 544 + q * 136 + nn * 8];
            short8 bh = *(const short8*)(bt0 + ks * 512);
            short8 bl = *(const short8*)(bt1 + ks * 512);
            acc = __builtin_amdgcn_mfma_f32_16x16x32_bf16(ah, bh, acc, 0, 0, 0);
            acc = __builtin_amdgcn_mfma_f32_16x16x32_bf16(ah, bl, acc, 0, 0, 0);
        }
        // D: col f = w*16+nn, row = t0 + tile*16 + q*4 + r
        #pragma unroll
        for (int r = 0; r < 4; ++r) {
            int row = t0 + tile * 16 + q * 4 + r;
            if (row < n_nodes) {
                if (last_layer)
                    out[(size_t)row * 64 + w * 16 + nn] = acc[r];
                else
                    hnext[(size_t)row * 64 + w * 16 + nn] = f2bf(acc[r]);
            }
        }
    }
}

extern "C" void kernel_launch(void* const* d_in, const int* in_sizes, int n_in,
                              void* d_out, int out_size, void* d_ws, size_t ws_size,
                              hipStream_t stream)
{
    const float* feat   = (const float*)d_in[0];   // [N, 64]
    const float* pseudo = (const float*)d_in[1];   // [E, 2]
    const int*   rowptr = (const int*)d_in[2];     // [N+1]
    const int*   colind = (const int*)d_in[3];     // [E]
    const float* projW  = (const float*)d_in[4];   // [L, 2, 2]
    const float* projB  = (const float*)d_in[5];   // [L, 2]
    const float* fcW    = (const float*)d_in[6];   // [L, 64, 192]
    const float* mu     = (const float*)d_in[7];   // [L, 3, 2]
    const float* isg    = (const float*)d_in[8];   // [L, 3, 2]
    float* out = (float*)d_out;

    int n  = in_sizes[0] / FEAT;                        // 50000
    int e  = in_sizes[3];                               // 1.6M
    int n_layers = in_sizes[6] / (FEAT * NKERN * FEAT); // 3

    unsigned short* hbA = (unsigned short*)d_ws;                  // n*64
    unsigned short* hbB = hbA + (size_t)n * FEAT;                 // n*64
    unsigned short* Bth = hbB + (size_t)n * FEAT;                 // L*12288
    unsigned short* Btl = Bth + (size_t)n_layers * 12288;         // L*12288
    float* wbuf3 = (float*)(Btl + (size_t)n_layers * 12288);      // L*e*3

    int castN4 = n * FEAT / 4;
    int wpN    = n_layers * FEAT * 192;
    int prepTotal = castN4 + wpN + e;

    dim3 blk(256);
    dim3 prepGrid((prepTotal + 255) / 256);
    dim3 layerGrid((n + 31) / 32);
    dim3 layerBlk(1024);

    prep_kernel<<<prepGrid, blk, 0, stream>>>(
        feat, hbA, fcW, Bth, Btl, pseudo, projW, projB, mu, isg, wbuf3,
        castN4, wpN, e, n_layers);

    const unsigned short* hin = hbA;
    for (int l = 0; l < n_layers; ++l) {
        int last = (l == n_layers - 1);
        unsigned short* hb_out = (l == 0) ? hbB : hbA;
        layer_kernel<<<layerGrid, layerBlk, 0, stream>>>(
            hin, rowptr, colind, wbuf3 + (size_t)l * e * 3,
            Bth + (size_t)l * 12288, Btl + (size_t)l * 12288,
            out, hb_out, n, last);
        hin = hb_out;
    }
}

// Round 13
// 267.614 us; speedup vs baseline: 1.5630x; 1.3402x over previous
//
#include <hip/hip_runtime.h>
#include <math.h>

#define FEAT 64
#define NKERN 3

typedef __attribute__((ext_vector_type(8))) short short8;
typedef __attribute__((ext_vector_type(4))) float float4v;

__device__ __forceinline__ unsigned short f2bf(float f) {
    unsigned int u = __float_as_uint(f);
    u = (u + 0x7fffu + ((u >> 16) & 1u)) >> 16;   // round-to-nearest-even
    return (unsigned short)u;
}
__device__ __forceinline__ float bf2f(unsigned short b) {
    return __uint_as_float(((unsigned int)b) << 16);
}
__device__ __forceinline__ float tanh_fast(float x) {
    x = fminf(fmaxf(x, -20.f), 20.f);
    float ex = exp2f(x * 2.885390082f);      // e^(2x)
    return (ex - 1.f) / (ex + 1.f);
}
__device__ __forceinline__ float exp_fast(float x) {
    return exp2f(x * 1.44269504f);
}

// Fused prep: [0,castN4) bf16-cast of feat; [castN4,+wpN) fcW -> frag-tiled
// B hi/lo; [+wpN, +e) per-edge Gaussian weights for all layers (fast math).
__global__ __launch_bounds__(256) void prep_kernel(
    const float* __restrict__ feat, unsigned short* __restrict__ h0,
    const float* __restrict__ fcW,
    unsigned short* __restrict__ Bth, unsigned short* __restrict__ Btl,
    const float* __restrict__ pseudo,
    const float* __restrict__ projW, const float* __restrict__ projB,
    const float* __restrict__ mu, const float* __restrict__ isg,
    float* __restrict__ wbuf3,
    int castN4, int wpN, int n_edges, int n_layers)
{
    int idx = blockIdx.x * 256 + threadIdx.x;
    if (idx < castN4) {
        float4 v = ((const float4*)feat)[idx];
        ushort4 o;
        o.x = f2bf(v.x); o.y = f2bf(v.y); o.z = f2bf(v.z); o.w = f2bf(v.w);
        ((ushort4*)h0)[idx] = o;
        return;
    }
    idx -= castN4;
    if (idx < wpN) {
        int l   = idx / (FEAT * 192);
        int rem = idx - l * (FEAT * 192);
        int f   = rem / 192;
        int jp  = rem - f * 192;
        int k = jp >> 6, j = jp & 63;
        float v = fcW[(size_t)l * 12288 + j * 192 + k * 64 + f];
        unsigned short hi = f2bf(v);
        int dst = l * 12288 +
                  ((((f >> 4) * 6 + (jp >> 5)) * 4 + ((jp >> 3) & 3)) * 16 + (f & 15)) * 8 +
                  (jp & 7);
        Bth[dst] = hi;
        Btl[dst] = f2bf(v - bf2f(hi));
        return;
    }
    idx -= wpN;
    if (idx >= n_edges) return;
    float2 p = ((const float2*)pseudo)[idx];
    for (int l = 0; l < n_layers; ++l) {
        const float* pw = projW + l * 4;
        const float* pb = projB + l * 2;
        const float* m_ = mu  + l * 6;
        const float* s_ = isg + l * 6;
        float u0 = tanh_fast(fmaf(p.x, pw[0], fmaf(p.y, pw[2], pb[0])));
        float u1 = tanh_fast(fmaf(p.x, pw[1], fmaf(p.y, pw[3], pb[1])));
        float d0, d1, s0, s1;
        d0 = u0 - m_[0]; d1 = u1 - m_[1]; s0 = s_[0]; s1 = s_[1];
        float w0 = exp_fast(-0.5f * (d0*d0*s0*s0 + d1*d1*s1*s1));
        d0 = u0 - m_[2]; d1 = u1 - m_[3]; s0 = s_[2]; s1 = s_[3];
        float w1 = exp_fast(-0.5f * (d0*d0*s0*s0 + d1*d1*s1*s1));
        d0 = u0 - m_[4]; d1 = u1 - m_[5]; s0 = s_[4]; s1 = s_[5];
        float w2 = exp_fast(-0.5f * (d0*d0*s0*s0 + d1*d1*s1*s1));
        float* wp = wbuf3 + ((size_t)l * n_edges + idx) * 3;
        wp[0] = w0; wp[1] = w1; wp[2] = w2;
    }
}

// One fused layer. Block = 16 waves = 16 nodes = one MFMA row-tile (R10
// structure). Gather addressing is VECTOR-pipe only: lane i vector-loads
// colind[r0+i] (1 coalesced 128B load), cc broadcast per edge via
// ds_bpermute (VGPR->VGPR, in-order, no SGPR chains, no SMEM waits) ->
// 32-bit voffset -> global_load with shared SGPR h-base. All 32 gathers
// stay in flight. Weights remain on s_load (consumed late; latency hidden).
__global__ __launch_bounds__(1024, 4) void layer_kernel(
    const unsigned short* __restrict__ h,    // [N, 64] bf16
    const int*   __restrict__ rowptr,        // [N+1]
    const int*   __restrict__ colind,        // [E]
    const float* __restrict__ wbuf,          // [E, 3] this layer
    const unsigned short* __restrict__ Bth,  // frag-tiled, this layer
    const unsigned short* __restrict__ Btl,
    float* __restrict__ out,                 // [N,64] fp32 (last layer)
    unsigned short* __restrict__ hnext,      // [N,64] bf16 (mid layers)
    int n_nodes, int last_layer)
{
    __shared__ __align__(16) unsigned short Atile[6 * 544];  // padded frag tile
    int tid  = threadIdx.x;
    int wv   = tid >> 6;          // 0..15 = node row m within tile
    int lane = tid & 63;
    int t0   = blockIdx.x * 16;
    int node = t0 + wv;

    float a0 = 0.f, a1 = 0.f, a2 = 0.f;
    if (node < n_nodes) {
        int nu  = __builtin_amdgcn_readfirstlane(node);
        int r0  = rowptr[nu];
        int deg = rowptr[nu + 1] - r0;   // fixed 32 in this problem
        if (deg == 32) {
            // lane i (i<32; duplicated for 32-63) holds colind[r0+i]
            int ccv = colind[r0 + (lane & 31)];
            unsigned short v[32];
            #pragma unroll
            for (int i = 0; i < 32; ++i) {
                int cc = __builtin_amdgcn_ds_bpermute(i * 4, ccv); // broadcast
                v[i] = h[(cc << 6) + lane];     // saddr + 32-bit voffset
            }
            #pragma unroll
            for (int i = 0; i < 32; ++i) {
                const float* wp = wbuf + (size_t)(r0 + i) * 3;  // uniform s_load
                float vf = bf2f(v[i]);
                a0 = fmaf(wp[0], vf, a0);
                a1 = fmaf(wp[1], vf, a1);
                a2 = fmaf(wp[2], vf, a2);
            }
        } else {
            for (int i = 0; i < deg; ++i) {
                int cc = colind[r0 + i];
                float vf = bf2f(h[(size_t)cc * FEAT + lane]);
                const float* wp = wbuf + (size_t)(r0 + i) * 3;
                a0 = fmaf(wp[0], vf, a0);
                a1 = fmaf(wp[1], vf, a1);
                a2 = fmaf(wp[2], vf, a2);
            }
        }
    }
    // padded A-frag store: jp=lane(+64,+128): ks=jp>>5, q=(jp>>3)&3, e=jp&7
    int base = (lane >> 5) * 544 + ((lane >> 3) & 3) * 136 + wv * 8 + (lane & 7);
    Atile[base]        = f2bf(a0);
    Atile[base + 1088] = f2bf(a1);   // +2 ks blocks
    Atile[base + 2176] = f2bf(a2);   // +4 ks blocks
    __syncthreads();

    if (wv < 4) {
        int w  = wv;            // f-tile
        int q  = lane >> 4;
        int nn = lane & 15;
        const unsigned short* bt0 = Bth + (((w * 6) * 4 + q) * 16 + nn) * 8;
        const unsigned short* bt1 = Btl + (((w * 6) * 4 + q) * 16 + nn) * 8;
        float4v acc = (float4v){0.f, 0.f, 0.f, 0.f};
        #pragma unroll
        for (int ks = 0; ks < 6; ++ks) {
            short8 ah = *(const short8*)&Atile[ks * 544 + q * 136 + nn * 8];
            short8 bh = *(const short8*)(bt0 + ks * 512);
            short8 bl = *(const short8*)(bt1 + ks * 512);
            acc = __builtin_amdgcn_mfma_f32_16x16x32_bf16(ah, bh, acc, 0, 0, 0);
            acc = __builtin_amdgcn_mfma_f32_16x16x32_bf16(ah, bl, acc, 0, 0, 0);
        }
        // D: col f = w*16+nn, row = t0 + q*4 + r
        #pragma unroll
        for (int r = 0; r < 4; ++r) {
            int row = t0 + q * 4 + r;
            if (row < n_nodes) {
                if (last_layer)
                    out[(size_t)row * 64 + w * 16 + nn] = acc[r];
                else
                    hnext[(size_t)row * 64 + w * 16 + nn] = f2bf(acc[r]);
            }
        }
    }
}

extern "C" void kernel_launch(void* const* d_in, const int* in_sizes, int n_in,
                              void* d_out, int out_size, void* d_ws, size_t ws_size,
                              hipStream_t stream)
{
    const float* feat   = (const float*)d_in[0];   // [N, 64]
    const float* pseudo = (const float*)d_in[1];   // [E, 2]
    const int*   rowptr = (const int*)d_in[2];     // [N+1]
    const int*   colind = (const int*)d_in[3];     // [E]
    const float* projW  = (const float*)d_in[4];   // [L, 2, 2]
    const float* projB  = (const float*)d_in[5];   // [L, 2]
    const float* fcW    = (const float*)d_in[6];   // [L, 64, 192]
    const float* mu     = (const float*)d_in[7];   // [L, 3, 2]
    const float* isg    = (const float*)d_in[8];   // [L, 3, 2]
    float* out = (float*)d_out;

    int n  = in_sizes[0] / FEAT;                        // 50000
    int e  = in_sizes[3];                               // 1.6M
    int n_layers = in_sizes[6] / (FEAT * NKERN * FEAT); // 3

    unsigned short* hbA = (unsigned short*)d_ws;                  // n*64
    unsigned short* hbB = hbA + (size_t)n * FEAT;                 // n*64
    unsigned short* Bth = hbB + (size_t)n * FEAT;                 // L*12288
    unsigned short* Btl = Bth + (size_t)n_layers * 12288;         // L*12288
    float* wbuf3 = (float*)(Btl + (size_t)n_layers * 12288);      // L*e*3

    int castN4 = n * FEAT / 4;
    int wpN    = n_layers * FEAT * 192;
    int prepTotal = castN4 + wpN + e;

    dim3 blk(256);
    dim3 prepGrid((prepTotal + 255) / 256);
    dim3 layerGrid((n + 15) / 16);
    dim3 layerBlk(1024);

    prep_kernel<<<prepGrid, blk, 0, stream>>>(
        feat, hbA, fcW, Bth, Btl, pseudo, projW, projB, mu, isg, wbuf3,
        castN4, wpN, e, n_layers);

    const unsigned short* hin = hbA;
    for (int l = 0; l < n_layers; ++l) {
        int last = (l == n_layers - 1);
        unsigned short* hb_out = (l == 0) ? hbB : hbA;
        layer_kernel<<<layerGrid, layerBlk, 0, stream>>>(
            hin, rowptr, colind, wbuf3 + (size_t)l * e * 3,
            Bth + (size_t)l * 12288, Btl + (size_t)l * 12288,
            out, hb_out, n, last);
        hin = hb_out;
    }
}